// Round 1
// baseline (181.692 us; speedup 1.0000x reference)
//
#include <hip/hip_runtime.h>
#include <math.h>

// B=2048, S=8, D=1280, K=1 rank-1 common-mode removal.
// R8: K1 was VALU-bound on the scalar hi/lo bf16 split at 1 wave/SIMD
// (~64 VALU per 8 elems -> ~3.4 B/cyc/CU << 10 needed for HBM peak).
// Fix: v_cvt_pk_bf16_f32 packed conversion (24 VALU per 8 elems, output
// already in bf16x8 operand layout) + 4-way K-split (4 waves/SIMD, full
// unroll keeps ~20 loads in flight). Gram partials land in 4 slots/batch;
// eigen sums them (linear, symmetrization commutes).
// G = HH + HL + HL^T where f = hi + lo; lo*lo^T ~ 2^-18 rel, dropped.
// Zero cross-lane / LDS ops anywhere (R2/R4/R5 plateaued ~50us on DS pipe).
//  K1 gram : 1 wave per (2 batches x 1/4 of K), 16x16 MFMA tile.
//  K2 eigen: 1 THREAD per batch, 8x8 in registers, constant-indexed arrays.
//  K3 apply: pure streaming.

#define SV 8
#define DV 1280
#define D4 320             // float4 per row
#define BSTRIDE (SV*DV)    // 10240 floats per batch
#define GSZ 136            // per-slot ws: HH[64] + HL[64] + S[8]
#define SPLIT 4            // K-split factor (waves per 2-batch pair)
#define CITER (40/SPLIT)   // 32-col chunks per wave
#define WSS 17             // per-batch coeffs: a[8], coef[8], bconst

typedef __attribute__((ext_vector_type(8))) short bf16x8;
typedef __attribute__((ext_vector_type(4))) float f32x4;

union BF8 { bf16x8 v; short s[8]; unsigned u[4]; };

__global__ __launch_bounds__(256)
void cmr_gram(const float* __restrict__ feat, float* __restrict__ gram)
{
    const int lane = threadIdx.x & 63;
    const int wid  = (blockIdx.x * 256 + threadIdx.x) >> 6;
    const int pair = wid >> 2;             // wid / SPLIT : which 2-batch pair
    const int h    = wid & (SPLIT - 1);    // which K-quarter
    const int m    = lane & 15;            // tile row/col: 0-7 batch0, 8-15 batch1
    const int quad = lane >> 4;            // k sub-offset = quad*8
    const int bt   = m >> 3;
    const int row  = m & 7;

    const float* __restrict__ fb =
        feat + ((size_t)(pair * 2 + bt)) * BSTRIDE + (size_t)row * DV;

    BF8 ones;
#pragma unroll
    for (int j = 0; j < 4; ++j) ones.u[j] = 0x3F803F80u;   // bf16 1.0 pairs

    f32x4 accHH = {0.f, 0.f, 0.f, 0.f};
    f32x4 accHL = {0.f, 0.f, 0.f, 0.f};
    f32x4 accS  = {0.f, 0.f, 0.f, 0.f};

#pragma unroll
    for (int c = 0; c < CITER; ++c) {
        const int k0 = (h * CITER + c) * 32 + quad * 8;
        const float4 x0 = *(const float4*)(fb + k0);
        const float4 x1 = *(const float4*)(fb + k0 + 4);
        float x[8] = {x0.x, x0.y, x0.z, x0.w, x1.x, x1.y, x1.z, x1.w};
        BF8 hi, lo;
#pragma unroll
        for (int j = 0; j < 4; ++j) {
            unsigned hp, lp;
            // hi = bf16(x) packed: bf(x[2j]) low16, bf(x[2j+1]) high16
            asm("v_cvt_pk_bf16_f32 %0, %1, %2" : "=v"(hp) : "v"(x[2*j]), "v"(x[2*j+1]));
            const float h0 = __uint_as_float(hp << 16);
            const float h1 = __uint_as_float(hp & 0xFFFF0000u);
            const float l0 = x[2*j]     - h0;   // exact-enough residual
            const float l1 = x[2*j + 1] - h1;
            asm("v_cvt_pk_bf16_f32 %0, %1, %2" : "=v"(lp) : "v"(l0), "v"(l1));
            hi.u[j] = hp;
            lo.u[j] = lp;
        }
        // HH[m][n] += sum_k hi[m]k hi[n]k ; HL[m][n] += sum_k hi[m]k lo[n]k
        accHH = __builtin_amdgcn_mfma_f32_16x16x32_bf16(hi.v, hi.v,   accHH, 0, 0, 0);
        accHL = __builtin_amdgcn_mfma_f32_16x16x32_bf16(hi.v, lo.v,   accHL, 0, 0, 0);
        // row sums: S[m] = sum_k (hi+lo)[m]k  (every column identical)
        accS  = __builtin_amdgcn_mfma_f32_16x16x32_bf16(hi.v, ones.v, accS,  0, 0, 0);
        accS  = __builtin_amdgcn_mfma_f32_16x16x32_bf16(lo.v, ones.v, accS,  0, 0, 0);
    }

    // C/D layout: lane l, reg r -> row=(l>>4)*4+r, col=l&15  [m89/m91]
    const int colb = (lane & 15) >> 3;
    const int col  = lane & 7;
#pragma unroll
    for (int r = 0; r < 4; ++r) {
        const int rowg = quad * 4 + r;            // 0..15
        if ((rowg >> 3) == colb) {                // same-batch diagonal blocks
            float* gb = gram + ((size_t)((pair * 2 + colb) * SPLIT + h)) * GSZ;
            gb[(rowg & 7) * 8 + col]      = accHH[r];
            gb[64 + (rowg & 7) * 8 + col] = accHL[r];
        }
    }
    if ((lane & 15) == 0) {                       // col-0 lanes: 0,16,32,48
#pragma unroll
        for (int r = 0; r < 4; ++r) {
            const int rowg = quad * 4 + r;
            gram[((size_t)((pair * 2 + (rowg >> 3)) * SPLIT + h)) * GSZ
                 + 128 + (rowg & 7)] = accS[r];
        }
    }
}

__global__ __launch_bounds__(64, 1)
void cmr_eigen(const float* __restrict__ gram,
               const float* __restrict__ kp,
               const float* __restrict__ cmr_gate,
               float* __restrict__ coef,
               float* __restrict__ out,
               int Bn)
{
    const int b = blockIdx.x * 64 + threadIdx.x;   // 1 thread = 1 batch
    const float* __restrict__ g = gram + (size_t)b * (GSZ * SPLIT);

    float G[8][8], S[8], mu[8], sig[8], rsig[8];
#pragma unroll
    for (int i = 0; i < 8; ++i) {
#pragma unroll
        for (int j = 0; j < 8; ++j) G[i][j] = 0.f;
        S[i] = 0.f;
    }
#pragma unroll
    for (int hh = 0; hh < SPLIT; ++hh) {
        const float* __restrict__ gh = g + hh * GSZ;
#pragma unroll
        for (int i = 0; i < 8; ++i) {
#pragma unroll
            for (int j = 0; j < 8; ++j)
                G[i][j] += gh[i * 8 + j] + gh[64 + i * 8 + j] + gh[64 + j * 8 + i];
            S[i] += gh[128 + i];
        }
    }
    const float invD = 1.f / (float)DV;
#pragma unroll
    for (int i = 0; i < 8; ++i) {
        mu[i] = S[i] * invD;
        const float var = fmaxf(G[i][i] * invD - mu[i] * mu[i], 0.f);
        sig[i]  = sqrtf(var) + 1e-8f;              // numpy std(ddof=0)+1e-8
        rsig[i] = 1.f / sig[i];
    }
    // normalize in place: G <- Gram of standardized rows
#pragma unroll
    for (int i = 0; i < 8; ++i)
#pragma unroll
        for (int j = 0; j < 8; ++j)
            G[i][j] = (G[i][j] - (float)DV * mu[i] * mu[j]) * rsig[i] * rsig[j];

    float tr = 0.f;
#pragma unroll
    for (int i = 0; i < 8; ++i) tr += G[i][i];

    // ---- 12x symmetric trace-normalized squaring (constant-indexed regs) ----
    float A[8][8];
    {
        const float rt = 1.f / fmaxf(tr, 1e-30f);
#pragma unroll
        for (int i = 0; i < 8; ++i)
#pragma unroll
            for (int j = 0; j < 8; ++j) A[i][j] = G[i][j] * rt;
    }
#pragma unroll
    for (int t = 0; t < 12; ++t) {
        float Bm[8][8];
        float trB = 0.f;
#pragma unroll
        for (int i = 0; i < 8; ++i)
#pragma unroll
            for (int j = i; j < 8; ++j) {
                float acc = 0.f;
#pragma unroll
                for (int k = 0; k < 8; ++k)
                    acc = fmaf(A[i][k], A[j][k], acc);   // A symmetric
                Bm[i][j] = acc;
                if (i == j) trB += acc;
            }
        const float rt = 1.f / fmaxf(trB, 1e-30f);
#pragma unroll
        for (int i = 0; i < 8; ++i)
#pragma unroll
            for (int j = i; j < 8; ++j) {
                const float v = Bm[i][j] * rt;
                A[i][j] = v; A[j][i] = v;
            }
    }
    // diag argmax -> dominant column ~ u1 (A ~= u u^T)
    int bj = 0; float best = A[0][0];
#pragma unroll
    for (int k = 1; k < 8; ++k)
        if (A[k][k] > best) { best = A[k][k]; bj = k; }
    float u[8];
#pragma unroll
    for (int i = 0; i < 8; ++i) {
        float v = A[i][0];
#pragma unroll
        for (int k = 1; k < 8; ++k) v = (bj == k) ? A[i][k] : v;
        u[i] = v;
    }
    {
        float nn = 0.f;
#pragma unroll
        for (int i = 0; i < 8; ++i) nn = fmaf(u[i], u[i], nn);
        const float r = rsqrtf(fmaxf(nn, 1e-30f));
#pragma unroll
        for (int i = 0; i < 8; ++i) u[i] *= r;
    }
    // 2 power-iteration polish steps on G
#pragma unroll
    for (int it = 0; it < 2; ++it) {
        float y[8]; float ny = 0.f;
#pragma unroll
        for (int i = 0; i < 8; ++i) {
            float acc = 0.f;
#pragma unroll
            for (int k = 0; k < 8; ++k) acc = fmaf(G[i][k], u[k], acc);
            y[i] = acc; ny = fmaf(acc, acc, ny);
        }
        const float r = rsqrtf(fmaxf(ny, 1e-30f));
#pragma unroll
        for (int i = 0; i < 8; ++i) u[i] = y[i] * r;
    }
    // Rayleigh quotient
    float lam = 0.f;
#pragma unroll
    for (int i = 0; i < 8; ++i) {
        float acc = 0.f;
#pragma unroll
        for (int k = 0; k < 8; ++k) acc = fmaf(G[i][k], u[k], acc);
        lam = fmaf(u[i], acc, lam);
    }
    const float pc1 = lam / (tr + 1e-8f);

    const float gate = 1.f / (1.f + expf(-cmr_gate[0]));
    const float kpg  = (kp[b] >= 5.0f) ? 1.5f : 1.0f;
    const float Gt   = gate * kpg;

    float bc = 0.f;
#pragma unroll
    for (int i = 0; i < 8; ++i) bc = fmaf(u[i] * rsig[i], mu[i], bc);

    float* wsb = coef + (size_t)b * WSS;
#pragma unroll
    for (int i = 0; i < 8; ++i) {
        wsb[i]     = u[i] * rsig[i];     // a_i   : p = sum a_s f[s,d] - bc
        wsb[8 + i] = Gt * sig[i] * u[i]; // coef_i: out = f - coef_s * p
    }
    wsb[16] = bc;
    out[(size_t)Bn * BSTRIDE + b] = pc1;
    out[(size_t)Bn * BSTRIDE + Bn + b] =
        (pc1 >= 0.6f ? 1.f : 0.f) + (pc1 >= 0.8f ? 1.f : 0.f);
}

__global__ __launch_bounds__(320)
void cmr_apply(const float* __restrict__ feat,
               const float* __restrict__ coef,
               float* __restrict__ out)
{
    const int tid  = threadIdx.x;
    const int lane = tid & 63;
    const int wq   = tid >> 6;
    const int b    = blockIdx.x;

    const float* __restrict__ wsb = coef + (size_t)b * WSS;  // uniform -> s-loads
    float a[8], c[8];
#pragma unroll
    for (int s = 0; s < 8; ++s) { a[s] = wsb[s]; c[s] = wsb[8 + s]; }
    const float bc = wsb[16];

    const float4* __restrict__ f4 = (const float4*)(feat + (size_t)b * BSTRIDE);
    float4* __restrict__ o4 = (float4*)(out + (size_t)b * BSTRIDE);
    const int d4 = wq * 64 + lane;

    float4 f[8];
#pragma unroll
    for (int s = 0; s < 8; ++s) f[s] = f4[s * D4 + d4];

    float4 p = make_float4(-bc, -bc, -bc, -bc);
#pragma unroll
    for (int s = 0; s < 8; ++s) {
        p.x = fmaf(a[s], f[s].x, p.x);
        p.y = fmaf(a[s], f[s].y, p.y);
        p.z = fmaf(a[s], f[s].z, p.z);
        p.w = fmaf(a[s], f[s].w, p.w);
    }
#pragma unroll
    for (int s = 0; s < 8; ++s) {
        float4 o;
        o.x = fmaf(-c[s], p.x, f[s].x);
        o.y = fmaf(-c[s], p.y, f[s].y);
        o.z = fmaf(-c[s], p.z, f[s].z);
        o.w = fmaf(-c[s], p.w, f[s].w);
        o4[s * D4 + d4] = o;
    }
}

extern "C" void kernel_launch(void* const* d_in, const int* in_sizes, int n_in,
                              void* d_out, int out_size, void* d_ws, size_t ws_size,
                              hipStream_t stream) {
    const float* feat = (const float*)d_in[0];
    const float* kp   = (const float*)d_in[1];
    const float* gate = (const float*)d_in[2];
    float* out = (float*)d_out;
    const int Bn = in_sizes[0] / BSTRIDE;        // 2048

    float* gram = (float*)d_ws;                        // Bn*SPLIT*136 floats
    float* coef = gram + (size_t)Bn * GSZ * SPLIT;     // Bn*17 floats

    cmr_gram <<<(Bn / 8) * SPLIT, 256, 0, stream>>>(feat, gram);  // 4 waves per pair
    cmr_eigen<<<Bn / 64, 64,  0, stream>>>(gram, kp, gate, coef, out, Bn);
    cmr_apply<<<Bn,      320, 0, stream>>>(feat, coef, out);
}

// Round 2
// 177.965 us; speedup vs baseline: 1.0209x; 1.0209x over previous
//
#include <hip/hip_runtime.h>
#include <math.h>

// B=2048, S=8, D=1280, K=1 rank-1 common-mode removal.
// R9: FUSED single kernel. R8 post-mortem: gram was ~5us, not 35 (bad
// arithmetic); the 3-kernel split pays two device-wide syncs, a gram/coef
// workspace round-trip, and a 32-wave eigen dispatch. Fusing gram->eigen->
// apply per 2-batch block removes all three: gram partials go to 4.3KB LDS
// (R8's MFMA code unchanged, 4 waves = K-split), eigen runs on wave0/lanes0-1
// out of LDS (chain overlaps other blocks' streaming), apply re-reads feat
// (L2/L3-hot after phase A) and streams out. One dispatch, zero workspace.
// G = HH + HL + HL^T where f = hi + lo; lo*lo^T ~ 2^-18 rel, dropped.
//  Phase A: 1 wave per (2 batches x 1/4 of K), 16x16 MFMA tile -> LDS.
//  Phase B: eigen, 1 LANE per batch, 8x8 in registers, constant-indexed.
//  Phase C: streaming apply, 256 threads over 640 float4-columns.

#define SV 8
#define DV 1280
#define D4 320             // float4 per row
#define BSTRIDE (SV*DV)    // 10240 floats per batch
#define GSZ 136            // per-slot: HH[64] + HL[64] + S[8]
#define SPLIT 4            // K-split factor = waves per block
#define CITER (40/SPLIT)   // 32-col chunks per wave

typedef __attribute__((ext_vector_type(8))) short bf16x8;
typedef __attribute__((ext_vector_type(4))) float f32x4;

union BF8 { bf16x8 v; short s[8]; unsigned u[4]; };

__global__ __launch_bounds__(256, 2)
void cmr_fused(const float* __restrict__ feat,
               const float* __restrict__ kp,
               const float* __restrict__ cmr_gate,
               float* __restrict__ out, int Bn)
{
    __shared__ float lg[SPLIT][2][GSZ];   // per-wave gram partials (4.25KB)
    __shared__ float lc[2][17];           // a[8], coef[8], bconst per batch

    const int tid  = threadIdx.x;
    const int lane = tid & 63;
    const int h    = tid >> 6;            // wave id = K-quarter
    const int pair = blockIdx.x;          // 2 batches per block

    // ---------------- Phase A: MFMA gram partials -> LDS ----------------
    {
        const int m    = lane & 15;       // tile row/col: 0-7 batch0, 8-15 batch1
        const int quad = lane >> 4;       // k sub-offset = quad*8
        const int bt   = m >> 3;
        const int row  = m & 7;

        const float* __restrict__ fb =
            feat + ((size_t)(pair * 2 + bt)) * BSTRIDE + (size_t)row * DV;

        BF8 ones;
#pragma unroll
        for (int j = 0; j < 4; ++j) ones.u[j] = 0x3F803F80u;   // bf16 1.0 pairs

        f32x4 accHH = {0.f, 0.f, 0.f, 0.f};
        f32x4 accHL = {0.f, 0.f, 0.f, 0.f};
        f32x4 accS  = {0.f, 0.f, 0.f, 0.f};

#pragma unroll
        for (int c = 0; c < CITER; ++c) {
            const int k0 = (h * CITER + c) * 32 + quad * 8;
            const float4 x0 = *(const float4*)(fb + k0);
            const float4 x1 = *(const float4*)(fb + k0 + 4);
            float x[8] = {x0.x, x0.y, x0.z, x0.w, x1.x, x1.y, x1.z, x1.w};
            BF8 hi, lo;
#pragma unroll
            for (int j = 0; j < 4; ++j) {
                unsigned hp, lp;
                asm("v_cvt_pk_bf16_f32 %0, %1, %2"
                    : "=v"(hp) : "v"(x[2*j]), "v"(x[2*j+1]));
                const float h0 = __uint_as_float(hp << 16);
                const float h1 = __uint_as_float(hp & 0xFFFF0000u);
                const float l0 = x[2*j]     - h0;
                const float l1 = x[2*j + 1] - h1;
                asm("v_cvt_pk_bf16_f32 %0, %1, %2"
                    : "=v"(lp) : "v"(l0), "v"(l1));
                hi.u[j] = hp;
                lo.u[j] = lp;
            }
            accHH = __builtin_amdgcn_mfma_f32_16x16x32_bf16(hi.v, hi.v,   accHH, 0, 0, 0);
            accHL = __builtin_amdgcn_mfma_f32_16x16x32_bf16(hi.v, lo.v,   accHL, 0, 0, 0);
            accS  = __builtin_amdgcn_mfma_f32_16x16x32_bf16(hi.v, ones.v, accS,  0, 0, 0);
            accS  = __builtin_amdgcn_mfma_f32_16x16x32_bf16(lo.v, ones.v, accS,  0, 0, 0);
        }

        // C/D layout: lane l, reg r -> row=(l>>4)*4+r, col=l&15  [m89/m91]
        const int colb = (lane & 15) >> 3;
        const int col  = lane & 7;
#pragma unroll
        for (int r = 0; r < 4; ++r) {
            const int rowg = quad * 4 + r;            // 0..15
            if ((rowg >> 3) == colb) {                // same-batch diagonal blocks
                lg[h][colb][(rowg & 7) * 8 + col]      = accHH[r];
                lg[h][colb][64 + (rowg & 7) * 8 + col] = accHL[r];
            }
        }
        if ((lane & 15) == 0) {                       // col-0 lanes: 0,16,32,48
#pragma unroll
            for (int r = 0; r < 4; ++r) {
                const int rowg = quad * 4 + r;
                lg[h][rowg >> 3][128 + (rowg & 7)] = accS[r];
            }
        }
    }
    __syncthreads();

    // ---------------- Phase B: eigen, 1 lane per batch ----------------
    if (h == 0 && lane < 2) {
        const int b2 = lane;
        const int b  = pair * 2 + b2;

        float G[8][8], S[8], mu[8], sig[8], rsig[8];
#pragma unroll
        for (int i = 0; i < 8; ++i) {
#pragma unroll
            for (int j = 0; j < 8; ++j) G[i][j] = 0.f;
            S[i] = 0.f;
        }
#pragma unroll
        for (int hh = 0; hh < SPLIT; ++hh) {
            const float* __restrict__ gh = &lg[hh][b2][0];
#pragma unroll
            for (int i = 0; i < 8; ++i) {
#pragma unroll
                for (int j = 0; j < 8; ++j)
                    G[i][j] += gh[i * 8 + j] + gh[64 + i * 8 + j] + gh[64 + j * 8 + i];
                S[i] += gh[128 + i];
            }
        }
        const float invD = 1.f / (float)DV;
#pragma unroll
        for (int i = 0; i < 8; ++i) {
            mu[i] = S[i] * invD;
            const float var = fmaxf(G[i][i] * invD - mu[i] * mu[i], 0.f);
            sig[i]  = sqrtf(var) + 1e-8f;              // numpy std(ddof=0)+1e-8
            rsig[i] = 1.f / sig[i];
        }
#pragma unroll
        for (int i = 0; i < 8; ++i)
#pragma unroll
            for (int j = 0; j < 8; ++j)
                G[i][j] = (G[i][j] - (float)DV * mu[i] * mu[j]) * rsig[i] * rsig[j];

        float tr = 0.f;
#pragma unroll
        for (int i = 0; i < 8; ++i) tr += G[i][i];

        // ---- 12x symmetric trace-normalized squaring ----
        float A[8][8];
        {
            const float rt = 1.f / fmaxf(tr, 1e-30f);
#pragma unroll
            for (int i = 0; i < 8; ++i)
#pragma unroll
                for (int j = 0; j < 8; ++j) A[i][j] = G[i][j] * rt;
        }
#pragma unroll
        for (int t = 0; t < 12; ++t) {
            float Bm[8][8];
            float trB = 0.f;
#pragma unroll
            for (int i = 0; i < 8; ++i)
#pragma unroll
                for (int j = i; j < 8; ++j) {
                    float acc = 0.f;
#pragma unroll
                    for (int k = 0; k < 8; ++k)
                        acc = fmaf(A[i][k], A[j][k], acc);   // A symmetric
                    Bm[i][j] = acc;
                    if (i == j) trB += acc;
                }
            const float rt = 1.f / fmaxf(trB, 1e-30f);
#pragma unroll
            for (int i = 0; i < 8; ++i)
#pragma unroll
                for (int j = i; j < 8; ++j) {
                    const float v = Bm[i][j] * rt;
                    A[i][j] = v; A[j][i] = v;
                }
        }
        // diag argmax -> dominant column ~ u1 (A ~= u u^T)
        int bj = 0; float best = A[0][0];
#pragma unroll
        for (int k = 1; k < 8; ++k)
            if (A[k][k] > best) { best = A[k][k]; bj = k; }
        float u[8];
#pragma unroll
        for (int i = 0; i < 8; ++i) {
            float v = A[i][0];
#pragma unroll
            for (int k = 1; k < 8; ++k) v = (bj == k) ? A[i][k] : v;
            u[i] = v;
        }
        {
            float nn = 0.f;
#pragma unroll
            for (int i = 0; i < 8; ++i) nn = fmaf(u[i], u[i], nn);
            const float r = rsqrtf(fmaxf(nn, 1e-30f));
#pragma unroll
            for (int i = 0; i < 8; ++i) u[i] *= r;
        }
        // 2 power-iteration polish steps on G
#pragma unroll
        for (int it = 0; it < 2; ++it) {
            float y[8]; float ny = 0.f;
#pragma unroll
            for (int i = 0; i < 8; ++i) {
                float acc = 0.f;
#pragma unroll
                for (int k = 0; k < 8; ++k) acc = fmaf(G[i][k], u[k], acc);
                y[i] = acc; ny = fmaf(acc, acc, ny);
            }
            const float r = rsqrtf(fmaxf(ny, 1e-30f));
#pragma unroll
            for (int i = 0; i < 8; ++i) u[i] = y[i] * r;
        }
        // Rayleigh quotient
        float lam = 0.f;
#pragma unroll
        for (int i = 0; i < 8; ++i) {
            float acc = 0.f;
#pragma unroll
            for (int k = 0; k < 8; ++k) acc = fmaf(G[i][k], u[k], acc);
            lam = fmaf(u[i], acc, lam);
        }
        const float pc1 = lam / (tr + 1e-8f);

        const float gate = 1.f / (1.f + expf(-cmr_gate[0]));
        const float kpg  = (kp[b] >= 5.0f) ? 1.5f : 1.0f;
        const float Gt   = gate * kpg;

        float bc = 0.f;
#pragma unroll
        for (int i = 0; i < 8; ++i) bc = fmaf(u[i] * rsig[i], mu[i], bc);

#pragma unroll
        for (int i = 0; i < 8; ++i) {
            lc[b2][i]     = u[i] * rsig[i];     // a_i   : p = sum a_s f[s,d] - bc
            lc[b2][8 + i] = Gt * sig[i] * u[i]; // coef_i: out = f - coef_s * p
        }
        lc[b2][16] = bc;
        out[(size_t)Bn * BSTRIDE + b] = pc1;
        out[(size_t)Bn * BSTRIDE + Bn + b] =
            (pc1 >= 0.6f ? 1.f : 0.f) + (pc1 >= 0.8f ? 1.f : 0.f);
    }
    __syncthreads();

    // ---------------- Phase C: streaming apply ----------------
    // 640 float4-column units: unit = b2*320 + col. feat is L2/L3-hot.
    for (int u = tid; u < 2 * D4; u += 256) {
        const int b2  = (u >= D4) ? 1 : 0;
        const int col = u - b2 * D4;

        float a[8], c[8];
#pragma unroll
        for (int s = 0; s < 8; ++s) { a[s] = lc[b2][s]; c[s] = lc[b2][8 + s]; }
        const float bc = lc[b2][16];

        const float4* __restrict__ f4 =
            (const float4*)(feat + (size_t)(pair * 2 + b2) * BSTRIDE);
        float4* __restrict__ o4 =
            (float4*)(out + (size_t)(pair * 2 + b2) * BSTRIDE);

        float4 f[8];
#pragma unroll
        for (int s = 0; s < 8; ++s) f[s] = f4[s * D4 + col];

        float4 p = make_float4(-bc, -bc, -bc, -bc);
#pragma unroll
        for (int s = 0; s < 8; ++s) {
            p.x = fmaf(a[s], f[s].x, p.x);
            p.y = fmaf(a[s], f[s].y, p.y);
            p.z = fmaf(a[s], f[s].z, p.z);
            p.w = fmaf(a[s], f[s].w, p.w);
        }
#pragma unroll
        for (int s = 0; s < 8; ++s) {
            float4 o;
            o.x = fmaf(-c[s], p.x, f[s].x);
            o.y = fmaf(-c[s], p.y, f[s].y);
            o.z = fmaf(-c[s], p.z, f[s].z);
            o.w = fmaf(-c[s], p.w, f[s].w);
            o4[s * D4 + col] = o;
        }
    }
}

extern "C" void kernel_launch(void* const* d_in, const int* in_sizes, int n_in,
                              void* d_out, int out_size, void* d_ws, size_t ws_size,
                              hipStream_t stream) {
    const float* feat = (const float*)d_in[0];
    const float* kp   = (const float*)d_in[1];
    const float* gate = (const float*)d_in[2];
    float* out = (float*)d_out;
    const int Bn = in_sizes[0] / BSTRIDE;        // 2048
    (void)d_ws; (void)ws_size;

    cmr_fused<<<Bn / 2, 256, 0, stream>>>(feat, kp, gate, out, Bn);
}